// Round 1
// baseline (1080.567 us; speedup 1.0000x reference)
//
#include <hip/hip_runtime.h>

#define NNODES 100000
#define NEDGES 1600000
#define DIM    128
#define NF     64
#define NG     50
#define NGP    52   // padded gaussian count (16B-aligned rows, zero-filled pad)
#define W2P    68   // enn2 row pad in floats (272B rows, 16B aligned, bank-staggered)

constexpr float F_CUTOFF = 5.0f;
constexpr float F_DELTA  = F_CUTOFF / (NG - 1);
constexpr float F_COEFF  = -0.5f / (F_DELTA * F_DELTA);
constexpr float F_PI     = 3.14159265358979323846f;

// ---------------- kernel 1: h[n][f] = sum_k x[n][k] * lin1_w[f][k] ----------------
__global__ __launch_bounds__(256) void k_lin1(
    const float* __restrict__ x, const float* __restrict__ w1,
    float* __restrict__ h) {
  __shared__ __align__(16) float sw[NF][DIM + 4];   // row stride 132 floats (528B)
  for (int i = threadIdx.x; i < NF * DIM; i += 256)
    sw[i >> 7][i & 127] = w1[i];
  __syncthreads();
  const int wave = threadIdx.x >> 6, lane = threadIdx.x & 63;
  const int nIter = NNODES / 4;            // 25000, 4 nodes per wave-iteration
  for (int it = blockIdx.x * 4 + wave; it < nIter; it += gridDim.x * 4) {
    const int n0 = it * 4;
    const float4* x0 = (const float4*)(x + (size_t)(n0 + 0) * DIM);
    const float4* x1 = (const float4*)(x + (size_t)(n0 + 1) * DIM);
    const float4* x2 = (const float4*)(x + (size_t)(n0 + 2) * DIM);
    const float4* x3 = (const float4*)(x + (size_t)(n0 + 3) * DIM);
    float a0 = 0.f, a1 = 0.f, a2 = 0.f, a3 = 0.f;
#pragma unroll 8
    for (int k4 = 0; k4 < DIM / 4; ++k4) {
      const float4 wv = *(const float4*)&sw[lane][k4 * 4];
      const float4 v0 = x0[k4], v1 = x1[k4], v2 = x2[k4], v3 = x3[k4];
      a0 = fmaf(v0.x, wv.x, a0); a0 = fmaf(v0.y, wv.y, a0);
      a0 = fmaf(v0.z, wv.z, a0); a0 = fmaf(v0.w, wv.w, a0);
      a1 = fmaf(v1.x, wv.x, a1); a1 = fmaf(v1.y, wv.y, a1);
      a1 = fmaf(v1.z, wv.z, a1); a1 = fmaf(v1.w, wv.w, a1);
      a2 = fmaf(v2.x, wv.x, a2); a2 = fmaf(v2.y, wv.y, a2);
      a2 = fmaf(v2.z, wv.z, a2); a2 = fmaf(v2.w, wv.w, a2);
      a3 = fmaf(v3.x, wv.x, a3); a3 = fmaf(v3.y, wv.y, a3);
      a3 = fmaf(v3.z, wv.z, a3); a3 = fmaf(v3.w, wv.w, a3);
    }
    h[(size_t)(n0 + 0) * NF + lane] = a0;
    h[(size_t)(n0 + 1) * NF + lane] = a1;
    h[(size_t)(n0 + 2) * NF + lane] = a2;
    h[(size_t)(n0 + 3) * NF + lane] = a3;
  }
}

// ---------------- kernel 2: edge MLP + gather + scatter-add ----------------
// 8 edges per wave-iteration; lane = filter index.
__global__ __launch_bounds__(256) void k_edge(
    const int* __restrict__ ei, const float* __restrict__ ew,
    const float* __restrict__ ea, const float* __restrict__ h,
    const float* __restrict__ w1, const float* __restrict__ b1,
    const float* __restrict__ w2, const float* __restrict__ b2,
    float* __restrict__ agg) {
  __shared__ __align__(16) float s_w1[NF][NGP];      // 64 x 52
  __shared__ __align__(16) float s_w2[NF][W2P];      // 64 x 68
  __shared__ __align__(16) float s_sm[4][8][NGP];    // per-wave: 8 edges x 52
  __shared__ __align__(16) float s_h1[4][8][NF];     // per-wave: 8 edges x 64

  for (int i = threadIdx.x; i < NF * NGP; i += 256) {
    int f = i / NGP, g = i - f * NGP;
    s_w1[f][g] = (g < NG) ? w1[f * NG + g] : 0.f;
  }
  for (int i = threadIdx.x; i < NF * W2P; i += 256) {
    int f = i / W2P, j = i - f * W2P;
    s_w2[f][j] = (j < NF) ? w2[f * NF + j] : 0.f;
  }
  __syncthreads();

  const int wave = threadIdx.x >> 6, lane = threadIdx.x & 63;
  const float b1f = b1[lane];
  const float b2f = b2[lane];
  float (* const my_sm)[NGP] = s_sm[wave];
  float (* const my_h1)[NF]  = s_h1[wave];

  const int nIter = NEDGES / 8;   // 200000
  for (int it = blockIdx.x * 4 + wave; it < nIter; it += gridDim.x * 4) {
    const int e0 = it * 8;
    // ---- gaussian smearing: lanes<50 each compute one gaussian per edge
#pragma unroll
    for (int e = 0; e < 8; ++e) {
      const float d = ea[e0 + e];                  // broadcast load
      if (lane < NG) {
        const float t = fmaf(-F_DELTA, (float)lane, d);
        my_sm[e][lane] = __expf(F_COEFF * t * t);
      } else if (lane < NGP) {
        my_sm[e][lane] = 0.f;                      // zero pad cols 50..51
      }
    }
    asm volatile("s_waitcnt lgkmcnt(0)" ::: "memory");

    // ---- phase 1: h1[e][lane] = relu(b1[lane] + w1[lane,:] . sm[e,:])
    float p1[8];
#pragma unroll
    for (int e = 0; e < 8; ++e) p1[e] = b1f;
#pragma unroll
    for (int g4 = 0; g4 < NGP / 4; ++g4) {
      const float4 wv = *(const float4*)&s_w1[lane][g4 * 4];
#pragma unroll
      for (int e = 0; e < 8; ++e) {
        const float4 m = *(const float4*)&my_sm[e][g4 * 4];
        p1[e] = fmaf(wv.x, m.x, p1[e]);
        p1[e] = fmaf(wv.y, m.y, p1[e]);
        p1[e] = fmaf(wv.z, m.z, p1[e]);
        p1[e] = fmaf(wv.w, m.w, p1[e]);
      }
    }
#pragma unroll
    for (int e = 0; e < 8; ++e)
      my_h1[e][lane] = fmaxf(p1[e], 0.f);
    asm volatile("s_waitcnt lgkmcnt(0)" ::: "memory");

    // ---- phase 2: W[e][lane] = b2[lane] + w2[lane,:] . h1[e,:]
    float p2[8];
#pragma unroll
    for (int e = 0; e < 8; ++e) p2[e] = b2f;
#pragma unroll
    for (int j4 = 0; j4 < NF / 4; ++j4) {
      const float4 wv = *(const float4*)&s_w2[lane][j4 * 4];
#pragma unroll
      for (int e = 0; e < 8; ++e) {
        const float4 hv = *(const float4*)&my_h1[e][j4 * 4];
        p2[e] = fmaf(wv.x, hv.x, p2[e]);
        p2[e] = fmaf(wv.y, hv.y, p2[e]);
        p2[e] = fmaf(wv.z, hv.z, p2[e]);
        p2[e] = fmaf(wv.w, hv.w, p2[e]);
      }
    }
    asm volatile("s_waitcnt lgkmcnt(0)" ::: "memory");  // done with my_sm/my_h1 before next iter

    // ---- cutoff + gather + scatter
#pragma unroll
    for (int e = 0; e < 8; ++e) {
      const float dw = ew[e0 + e];
      const float C  = 0.5f * (__cosf(dw * (F_PI / F_CUTOFF)) + 1.0f);
      const int   src = ei[e0 + e];
      const int   dst = ei[NEDGES + e0 + e];
      const float msg = h[(size_t)src * NF + lane] * (p2[e] * C);
      unsafeAtomicAdd(&agg[(size_t)dst * NF + lane], msg);
    }
  }
}

// ---------------- kernel 3: out[n][d] = x[n][d] + relu(b[d] + agg[n,:] . lin2_w[d,:]) ----------------
__global__ __launch_bounds__(256) void k_out(
    const float* __restrict__ x, const float* __restrict__ agg,
    const float* __restrict__ w2, const float* __restrict__ b,
    float* __restrict__ out) {
  __shared__ __align__(16) float sw[DIM][NF + 4];    // 128 x 68
  __shared__ __align__(16) float sa[4][4][NF];       // wave, node, j
  for (int i = threadIdx.x; i < DIM * NF; i += 256)
    sw[i >> 6][i & 63] = w2[i];
  __syncthreads();
  const int wave = threadIdx.x >> 6, lane = threadIdx.x & 63;
  const float bias0 = b[lane], bias1 = b[lane + 64];
  const int nIter = NNODES / 4;    // 25000
  for (int it = blockIdx.x * 4 + wave; it < nIter; it += gridDim.x * 4) {
    const int n0 = it * 4;
#pragma unroll
    for (int i = 0; i < 4; ++i)
      sa[wave][i][lane] = agg[(size_t)(n0 + i) * NF + lane];
    asm volatile("s_waitcnt vmcnt(0) lgkmcnt(0)" ::: "memory");
    float acc[8];
#pragma unroll
    for (int i = 0; i < 4; ++i) { acc[2 * i] = bias0; acc[2 * i + 1] = bias1; }
#pragma unroll
    for (int j4 = 0; j4 < NF / 4; ++j4) {
      const float4 wv0 = *(const float4*)&sw[lane][j4 * 4];
      const float4 wv1 = *(const float4*)&sw[lane + 64][j4 * 4];
#pragma unroll
      for (int i = 0; i < 4; ++i) {
        const float4 av = *(const float4*)&sa[wave][i][j4 * 4];   // broadcast
        acc[2 * i]     = fmaf(wv0.x, av.x, acc[2 * i]);
        acc[2 * i]     = fmaf(wv0.y, av.y, acc[2 * i]);
        acc[2 * i]     = fmaf(wv0.z, av.z, acc[2 * i]);
        acc[2 * i]     = fmaf(wv0.w, av.w, acc[2 * i]);
        acc[2 * i + 1] = fmaf(wv1.x, av.x, acc[2 * i + 1]);
        acc[2 * i + 1] = fmaf(wv1.y, av.y, acc[2 * i + 1]);
        acc[2 * i + 1] = fmaf(wv1.z, av.z, acc[2 * i + 1]);
        acc[2 * i + 1] = fmaf(wv1.w, av.w, acc[2 * i + 1]);
      }
    }
    asm volatile("s_waitcnt lgkmcnt(0)" ::: "memory");  // done with sa before next iter
#pragma unroll
    for (int i = 0; i < 4; ++i) {
      const size_t base = (size_t)(n0 + i) * DIM;
      out[base + lane]      = x[base + lane]      + fmaxf(acc[2 * i],     0.f);
      out[base + 64 + lane] = x[base + 64 + lane] + fmaxf(acc[2 * i + 1], 0.f);
    }
  }
}

extern "C" void kernel_launch(void* const* d_in, const int* in_sizes, int n_in,
                              void* d_out, int out_size, void* d_ws, size_t ws_size,
                              hipStream_t stream) {
  const float* x   = (const float*)d_in[0];
  const int*   ei  = (const int*)  d_in[1];   // [2][E] int32
  const float* ew  = (const float*)d_in[2];   // edge_weight (dist)
  const float* ea  = (const float*)d_in[3];   // edge_attr (dist)
  const float* l1w = (const float*)d_in[4];   // [64][128]
  const float* l2w = (const float*)d_in[5];   // [128][64]
  const float* l2b = (const float*)d_in[6];   // [128]
  const float* e1w = (const float*)d_in[7];   // [64][50]
  const float* e1b = (const float*)d_in[8];   // [64]
  const float* e2w = (const float*)d_in[9];   // [64][64]
  const float* e2b = (const float*)d_in[10];  // [64]
  float* out = (float*)d_out;

  float* h   = (float*)d_ws;                          // 100000*64 f32 = 25.6 MB
  float* agg = h + (size_t)NNODES * NF;               // 100000*64 f32 = 25.6 MB

  hipMemsetAsync(agg, 0, sizeof(float) * (size_t)NNODES * NF, stream);
  k_lin1<<<2048, 256, 0, stream>>>(x, l1w, h);
  k_edge<<<2048, 256, 0, stream>>>(ei, ew, ea, h, e1w, e1b, e2w, e2b, agg);
  k_out <<<2048, 256, 0, stream>>>(x, agg, l2w, l2b, out);
}

// Round 2
// 554.743 us; speedup vs baseline: 1.9479x; 1.9479x over previous
//
#include <hip/hip_runtime.h>

#define NNODES 100000
#define NEDGES 1600000
#define DIM    128
#define NF     64
#define NG     50

constexpr float F_CUTOFF = 5.0f;
constexpr float F_DELTA  = F_CUTOFF / (NG - 1);
constexpr float F_COEFF  = -0.5f / (F_DELTA * F_DELTA);
constexpr float F_PI     = 3.14159265358979323846f;

typedef __attribute__((ext_vector_type(8))) short short8v;
typedef __attribute__((ext_vector_type(4))) float f32x4;
typedef __attribute__((ext_vector_type(2))) int int2v;

__device__ inline unsigned short f2bf(float x) {
  unsigned int u = __float_as_uint(x);
  unsigned int r = (u + 0x7fffu + ((u >> 16) & 1u)) >> 16;
  return (unsigned short)r;
}

// ---------------- kernel 1: h[n][f] = sum_k x[n][k] * lin1_w[f][k] ----------------
__global__ __launch_bounds__(256) void k_lin1(
    const float* __restrict__ x, const float* __restrict__ w1,
    float* __restrict__ h) {
  __shared__ __align__(16) float sw[NF][DIM + 4];
  for (int i = threadIdx.x; i < NF * DIM; i += 256)
    sw[i >> 7][i & 127] = w1[i];
  __syncthreads();
  const int wave = threadIdx.x >> 6, lane = threadIdx.x & 63;
  const int nIter = NNODES / 4;
  for (int it = blockIdx.x * 4 + wave; it < nIter; it += gridDim.x * 4) {
    const int n0 = it * 4;
    const float4* x0 = (const float4*)(x + (size_t)(n0 + 0) * DIM);
    const float4* x1 = (const float4*)(x + (size_t)(n0 + 1) * DIM);
    const float4* x2 = (const float4*)(x + (size_t)(n0 + 2) * DIM);
    const float4* x3 = (const float4*)(x + (size_t)(n0 + 3) * DIM);
    float a0 = 0.f, a1 = 0.f, a2 = 0.f, a3 = 0.f;
#pragma unroll 8
    for (int k4 = 0; k4 < DIM / 4; ++k4) {
      const float4 wv = *(const float4*)&sw[lane][k4 * 4];
      const float4 v0 = x0[k4], v1 = x1[k4], v2 = x2[k4], v3 = x3[k4];
      a0 = fmaf(v0.x, wv.x, a0); a0 = fmaf(v0.y, wv.y, a0);
      a0 = fmaf(v0.z, wv.z, a0); a0 = fmaf(v0.w, wv.w, a0);
      a1 = fmaf(v1.x, wv.x, a1); a1 = fmaf(v1.y, wv.y, a1);
      a1 = fmaf(v1.z, wv.z, a1); a1 = fmaf(v1.w, wv.w, a1);
      a2 = fmaf(v2.x, wv.x, a2); a2 = fmaf(v2.y, wv.y, a2);
      a2 = fmaf(v2.z, wv.z, a2); a2 = fmaf(v2.w, wv.w, a2);
      a3 = fmaf(v3.x, wv.x, a3); a3 = fmaf(v3.y, wv.y, a3);
      a3 = fmaf(v3.z, wv.z, a3); a3 = fmaf(v3.w, wv.w, a3);
    }
    h[(size_t)(n0 + 0) * NF + lane] = a0;
    h[(size_t)(n0 + 1) * NF + lane] = a1;
    h[(size_t)(n0 + 2) * NF + lane] = a2;
    h[(size_t)(n0 + 3) * NF + lane] = a3;
  }
}

// ---------------- kernel 2: MFMA edge MLP + gather + scatter-add ----------------
// Per wave-iteration: 16 edges. M=edges(16), N=filters(64: 4 tiles), K padded to 64 (2 steps).
// A/B k-assignment: k = s*32 + (lane>>4)*8 + i  (only A/B agreement matters).
// C/D (verified): col n = lane&15, row m = (lane>>4)*4 + reg.
__global__ __launch_bounds__(256) void k_edge_mfma(
    const int* __restrict__ ei, const float* __restrict__ ew,
    const float* __restrict__ ea, const float* __restrict__ h,
    const float* __restrict__ w1, const float* __restrict__ b1,
    const float* __restrict__ w2, const float* __restrict__ b2,
    float* __restrict__ agg) {
  __shared__ __align__(16) unsigned short h1buf[4][NF][16];  // per-wave [f][e] bf16

  const int wave = threadIdx.x >> 6, lane = threadIdx.x & 63;
  const int lo = lane & 15, g = lane >> 4;

  // --- B1 fragments: B[k=gauss][n=f], value = w1[f][gauss] (0-padded past NG)
  short8v B1[4][2];
#pragma unroll
  for (int t = 0; t < 4; ++t)
#pragma unroll
    for (int s = 0; s < 2; ++s) {
      short8v f8;
#pragma unroll
      for (int i = 0; i < 8; ++i) {
        const int gg = s * 32 + g * 8 + i;
        const int f  = t * 16 + lo;
        f8[i] = (gg < NG) ? (short)f2bf(w1[f * NG + gg]) : (short)0;
      }
      B1[t][s] = f8;
    }
  // --- B2 fragments: B[k=f][n=j], value = w2[j][f]
  short8v B2[4][2];
#pragma unroll
  for (int t = 0; t < 4; ++t)
#pragma unroll
    for (int s = 0; s < 2; ++s) {
      short8v f8;
#pragma unroll
      for (int i = 0; i < 8; ++i) {
        const int f = s * 32 + g * 8 + i;
        const int j = t * 16 + lo;
        f8[i] = (short)f2bf(w2[j * NF + f]);
      }
      B2[t][s] = f8;
    }
  float b1v[4], b2v[4];
#pragma unroll
  for (int t = 0; t < 4; ++t) { b1v[t] = b1[t * 16 + lo]; b2v[t] = b2[t * 16 + lo]; }

  const float l2e_coeff = F_COEFF * 1.44269504088896341f;  // exp2 form

  const int nIter = NEDGES / 16;  // 100000
  for (int it = blockIdx.x * 4 + wave; it < nIter; it += gridDim.x * 4) {
    const int e0 = it * 16;
    const float d = ea[e0 + lo];   // this lane's edge (e = lo) distance

    // --- A1: smeared gaussians straight into fragment layout
    short8v A1[2];
#pragma unroll
    for (int s = 0; s < 2; ++s) {
      short8v f8;
#pragma unroll
      for (int i = 0; i < 8; ++i) {
        const int gg = s * 32 + g * 8 + i;
        const float t0 = d - (float)gg * F_DELTA;
        const float sm = exp2f(l2e_coeff * t0 * t0);
        f8[i] = (gg < NG) ? (short)f2bf(sm) : (short)0;
      }
      A1[s] = f8;
    }

    // --- phase 1 MFMA: h1[e][f]
    f32x4 acc1[4];
#pragma unroll
    for (int t = 0; t < 4; ++t) {
      f32x4 z = {0.f, 0.f, 0.f, 0.f};
      z = __builtin_amdgcn_mfma_f32_16x16x32_bf16(A1[0], B1[t][0], z, 0, 0, 0);
      z = __builtin_amdgcn_mfma_f32_16x16x32_bf16(A1[1], B1[t][1], z, 0, 0, 0);
      acc1[t] = z;
    }

    // --- relu + bias, pack to bf16, store [f][e] (lane: f = t*16+lo fixed, e = g*4..g*4+3)
#pragma unroll
    for (int t = 0; t < 4; ++t) {
      const float v0 = fmaxf(acc1[t][0] + b1v[t], 0.f);
      const float v1 = fmaxf(acc1[t][1] + b1v[t], 0.f);
      const float v2 = fmaxf(acc1[t][2] + b1v[t], 0.f);
      const float v3 = fmaxf(acc1[t][3] + b1v[t], 0.f);
      const unsigned int p0 = (unsigned)f2bf(v0) | ((unsigned)f2bf(v1) << 16);
      const unsigned int p1 = (unsigned)f2bf(v2) | ((unsigned)f2bf(v3) << 16);
      int2v pk; pk[0] = (int)p0; pk[1] = (int)p1;
      *(int2v*)&h1buf[wave][t * 16 + lo][g * 4] = pk;
    }

    // --- A2: read column slice (e = lo, f = s*32+g*8+i)
    short8v A2[2];
#pragma unroll
    for (int s = 0; s < 2; ++s) {
      short8v f8;
#pragma unroll
      for (int i = 0; i < 8; ++i)
        f8[i] = (short)h1buf[wave][s * 32 + g * 8 + i][lo];
      A2[s] = f8;
    }

    // --- phase 2 MFMA: W[e][j] (pre-bias)
    f32x4 acc2[4];
#pragma unroll
    for (int t = 0; t < 4; ++t) {
      f32x4 z = {0.f, 0.f, 0.f, 0.f};
      z = __builtin_amdgcn_mfma_f32_16x16x32_bf16(A2[0], B2[t][0], z, 0, 0, 0);
      z = __builtin_amdgcn_mfma_f32_16x16x32_bf16(A2[1], B2[t][1], z, 0, 0, 0);
      acc2[t] = z;
    }

    // --- cutoff + gather + scatter in MFMA layout: e = g*4 + r, j = t*16 + lo
#pragma unroll
    for (int r = 0; r < 4; ++r) {
      const int er = e0 + g * 4 + r;
      const float dw = ew[er];
      const float C  = 0.5f * (__cosf(dw * (F_PI / F_CUTOFF)) + 1.0f);
      const int src = ei[er];
      const int dst = ei[NEDGES + er];
      const size_t sb = (size_t)src * NF;
      const size_t db = (size_t)dst * NF;
#pragma unroll
      for (int t = 0; t < 4; ++t) {
        const float wv  = (acc2[t][r] + b2v[t]) * C;
        const float msg = h[sb + t * 16 + lo] * wv;
        unsafeAtomicAdd(&agg[db + t * 16 + lo], msg);
      }
    }
  }
}

// ---------------- kernel 3: out[n][d] = x[n][d] + relu(b[d] + agg[n,:] . lin2_w[d,:]) ----------------
__global__ __launch_bounds__(256) void k_out(
    const float* __restrict__ x, const float* __restrict__ agg,
    const float* __restrict__ w2, const float* __restrict__ b,
    float* __restrict__ out) {
  __shared__ __align__(16) float sw[DIM][NF + 4];
  __shared__ __align__(16) float sa[4][4][NF];
  for (int i = threadIdx.x; i < DIM * NF; i += 256)
    sw[i >> 6][i & 63] = w2[i];
  __syncthreads();
  const int wave = threadIdx.x >> 6, lane = threadIdx.x & 63;
  const float bias0 = b[lane], bias1 = b[lane + 64];
  const int nIter = NNODES / 4;
  for (int it = blockIdx.x * 4 + wave; it < nIter; it += gridDim.x * 4) {
    const int n0 = it * 4;
#pragma unroll
    for (int i = 0; i < 4; ++i)
      sa[wave][i][lane] = agg[(size_t)(n0 + i) * NF + lane];
    asm volatile("s_waitcnt vmcnt(0) lgkmcnt(0)" ::: "memory");
    float acc[8];
#pragma unroll
    for (int i = 0; i < 4; ++i) { acc[2 * i] = bias0; acc[2 * i + 1] = bias1; }
#pragma unroll
    for (int j4 = 0; j4 < NF / 4; ++j4) {
      const float4 wv0 = *(const float4*)&sw[lane][j4 * 4];
      const float4 wv1 = *(const float4*)&sw[lane + 64][j4 * 4];
#pragma unroll
      for (int i = 0; i < 4; ++i) {
        const float4 av = *(const float4*)&sa[wave][i][j4 * 4];
        acc[2 * i]     = fmaf(wv0.x, av.x, acc[2 * i]);
        acc[2 * i]     = fmaf(wv0.y, av.y, acc[2 * i]);
        acc[2 * i]     = fmaf(wv0.z, av.z, acc[2 * i]);
        acc[2 * i]     = fmaf(wv0.w, av.w, acc[2 * i]);
        acc[2 * i + 1] = fmaf(wv1.x, av.x, acc[2 * i + 1]);
        acc[2 * i + 1] = fmaf(wv1.y, av.y, acc[2 * i + 1]);
        acc[2 * i + 1] = fmaf(wv1.z, av.z, acc[2 * i + 1]);
        acc[2 * i + 1] = fmaf(wv1.w, av.w, acc[2 * i + 1]);
      }
    }
    asm volatile("s_waitcnt lgkmcnt(0)" ::: "memory");
#pragma unroll
    for (int i = 0; i < 4; ++i) {
      const size_t base = (size_t)(n0 + i) * DIM;
      out[base + lane]      = x[base + lane]      + fmaxf(acc[2 * i],     0.f);
      out[base + 64 + lane] = x[base + 64 + lane] + fmaxf(acc[2 * i + 1], 0.f);
    }
  }
}

extern "C" void kernel_launch(void* const* d_in, const int* in_sizes, int n_in,
                              void* d_out, int out_size, void* d_ws, size_t ws_size,
                              hipStream_t stream) {
  const float* x   = (const float*)d_in[0];
  const int*   ei  = (const int*)  d_in[1];
  const float* ew  = (const float*)d_in[2];
  const float* ea  = (const float*)d_in[3];
  const float* l1w = (const float*)d_in[4];
  const float* l2w = (const float*)d_in[5];
  const float* l2b = (const float*)d_in[6];
  const float* e1w = (const float*)d_in[7];
  const float* e1b = (const float*)d_in[8];
  const float* e2w = (const float*)d_in[9];
  const float* e2b = (const float*)d_in[10];
  float* out = (float*)d_out;

  float* h   = (float*)d_ws;
  float* agg = h + (size_t)NNODES * NF;

  hipMemsetAsync(agg, 0, sizeof(float) * (size_t)NNODES * NF, stream);
  k_lin1     <<<2048, 256, 0, stream>>>(x, l1w, h);
  k_edge_mfma<<<2048, 256, 0, stream>>>(ei, ew, ea, h, e1w, e1b, e2w, e2b, agg);
  k_out      <<<2048, 256, 0, stream>>>(x, agg, l2w, l2b, out);
}

// Round 3
// 372.041 us; speedup vs baseline: 2.9044x; 1.4911x over previous
//
#include <hip/hip_runtime.h>

#define NNODES 100000
#define NEDGES 1600000
#define DIM    128
#define NF     64
#define NG     50
#define H1P    20   // h1buf row stride in shorts (40B: 8B-aligned writes, ~conflict-free)

constexpr float F_CUTOFF = 5.0f;
constexpr float F_DELTA  = F_CUTOFF / (NG - 1);
constexpr float F_COEFF  = -0.5f / (F_DELTA * F_DELTA);
constexpr float F_PI     = 3.14159265358979323846f;

typedef __attribute__((ext_vector_type(8))) short short8v;
typedef __attribute__((ext_vector_type(4))) float f32x4;
typedef __attribute__((ext_vector_type(2))) int int2v;

__device__ inline unsigned short f2bf(float x) {
  unsigned int u = __float_as_uint(x);
  unsigned int r = (u + 0x7fffu + ((u >> 16) & 1u)) >> 16;
  return (unsigned short)r;
}
__device__ inline float bf2f(unsigned int lo16) {
  return __uint_as_float(lo16 << 16);
}

// ---------------- kernel 1: h[n][f] = sum_k x[n][k] * lin1_w[f][k]  (bf16 out) ----------------
__global__ __launch_bounds__(256) void k_lin1(
    const float* __restrict__ x, const float* __restrict__ w1,
    unsigned short* __restrict__ h) {
  __shared__ __align__(16) float sw[NF][DIM + 4];
  for (int i = threadIdx.x; i < NF * DIM; i += 256)
    sw[i >> 7][i & 127] = w1[i];
  __syncthreads();
  const int wave = threadIdx.x >> 6, lane = threadIdx.x & 63;
  const int nIter = NNODES / 4;
  for (int it = blockIdx.x * 4 + wave; it < nIter; it += gridDim.x * 4) {
    const int n0 = it * 4;
    const float4* x0 = (const float4*)(x + (size_t)(n0 + 0) * DIM);
    const float4* x1 = (const float4*)(x + (size_t)(n0 + 1) * DIM);
    const float4* x2 = (const float4*)(x + (size_t)(n0 + 2) * DIM);
    const float4* x3 = (const float4*)(x + (size_t)(n0 + 3) * DIM);
    float a0 = 0.f, a1 = 0.f, a2 = 0.f, a3 = 0.f;
#pragma unroll 8
    for (int k4 = 0; k4 < DIM / 4; ++k4) {
      const float4 wv = *(const float4*)&sw[lane][k4 * 4];
      const float4 v0 = x0[k4], v1 = x1[k4], v2 = x2[k4], v3 = x3[k4];
      a0 = fmaf(v0.x, wv.x, a0); a0 = fmaf(v0.y, wv.y, a0);
      a0 = fmaf(v0.z, wv.z, a0); a0 = fmaf(v0.w, wv.w, a0);
      a1 = fmaf(v1.x, wv.x, a1); a1 = fmaf(v1.y, wv.y, a1);
      a1 = fmaf(v1.z, wv.z, a1); a1 = fmaf(v1.w, wv.w, a1);
      a2 = fmaf(v2.x, wv.x, a2); a2 = fmaf(v2.y, wv.y, a2);
      a2 = fmaf(v2.z, wv.z, a2); a2 = fmaf(v2.w, wv.w, a2);
      a3 = fmaf(v3.x, wv.x, a3); a3 = fmaf(v3.y, wv.y, a3);
      a3 = fmaf(v3.z, wv.z, a3); a3 = fmaf(v3.w, wv.w, a3);
    }
    h[(size_t)(n0 + 0) * NF + lane] = f2bf(a0);
    h[(size_t)(n0 + 1) * NF + lane] = f2bf(a1);
    h[(size_t)(n0 + 2) * NF + lane] = f2bf(a2);
    h[(size_t)(n0 + 3) * NF + lane] = f2bf(a3);
  }
}

// ---------------- kernel 2: MFMA edge MLP + early gather + pk-bf16 scatter ----------------
// 16 edges/wave-iter. Phase1 tiles: f = t*16+lo (identity). Phase2 tiles are filter-pair
// permuted: col lo of tile t -> output filter j = (t>>1)*32 + 2*lo + (t&1), so a lane
// holds adjacent-filter pairs (2lo,2lo+1) and (32+2lo,33+2lo) -> packed-bf16 atomics.
// C/D layout (verified): col = lane&15, row = (lane>>4)*4 + reg.
__global__ __launch_bounds__(256, 4) void k_edge_mfma(
    const int* __restrict__ ei, const float* __restrict__ ew,
    const float* __restrict__ ea, const unsigned short* __restrict__ hbf,
    const float* __restrict__ w1, const float* __restrict__ b1,
    const float* __restrict__ w2, const float* __restrict__ b2,
    unsigned short* __restrict__ agg) {
  __shared__ __align__(16) unsigned short h1buf[4][NF][H1P];  // per-wave transpose buffer

  const int wave = threadIdx.x >> 6, lane = threadIdx.x & 63;
  const int lo = lane & 15, g = lane >> 4;

  // --- B1 fragments: B[k=gauss][n=f], f = t*16+lo, zero-padded past NG
  short8v B1[4][2];
#pragma unroll
  for (int t = 0; t < 4; ++t)
#pragma unroll
    for (int s = 0; s < 2; ++s) {
      short8v f8;
#pragma unroll
      for (int i = 0; i < 8; ++i) {
        const int gg = s * 32 + g * 8 + i;
        const int f  = t * 16 + lo;
        f8[i] = (gg < NG) ? (short)f2bf(w1[f * NG + gg]) : (short)0;
      }
      B1[t][s] = f8;
    }
  // --- B2 fragments: B[k=f_in][n], output filter j = (t>>1)*32 + 2*lo + (t&1)
  short8v B2[4][2];
#pragma unroll
  for (int t = 0; t < 4; ++t)
#pragma unroll
    for (int s = 0; s < 2; ++s) {
      short8v f8;
#pragma unroll
      for (int i = 0; i < 8; ++i) {
        const int f_in = s * 32 + g * 8 + i;
        const int j = (t >> 1) * 32 + 2 * lo + (t & 1);
        f8[i] = (short)f2bf(w2[j * NF + f_in]);
      }
      B2[t][s] = f8;
    }
  float b1v[4], b2v[4];
#pragma unroll
  for (int t = 0; t < 4; ++t) {
    b1v[t] = b1[t * 16 + lo];
    b2v[t] = b2[(t >> 1) * 32 + 2 * lo + (t & 1)];
  }

  const float l2e_coeff = F_COEFF * 1.44269504088896341f;  // exp2 form

  const int nIter = NEDGES / 16;  // 100000
  for (int it = blockIdx.x * 4 + wave; it < nIter; it += gridDim.x * 4) {
    const int e0 = it * 16;

    // ---- edge sources + EARLY gather: latency hides under the MLP compute
    int src[4];
#pragma unroll
    for (int r = 0; r < 4; ++r) src[r] = ei[e0 + g * 4 + r];
    unsigned int hp0[4], hp1[4];   // bf16 pairs: filters (2lo,2lo+1), (32+2lo,33+2lo)
#pragma unroll
    for (int r = 0; r < 4; ++r) {
      const unsigned short* hsrc = hbf + (size_t)src[r] * NF + 2 * lo;
      hp0[r] = *(const unsigned int*)(hsrc);
      hp1[r] = *(const unsigned int*)(hsrc + 32);
    }

    const float d = ea[e0 + lo];   // this lane's edge distance (e = lo)

    // ---- A1: gaussian smearing straight into fragment layout
    short8v A1[2];
#pragma unroll
    for (int s = 0; s < 2; ++s) {
      short8v f8;
#pragma unroll
      for (int i = 0; i < 8; ++i) {
        const int gg = s * 32 + g * 8 + i;
        const float t0 = d - (float)gg * F_DELTA;
        const float sm = exp2f(l2e_coeff * t0 * t0);
        f8[i] = (gg < NG) ? (short)f2bf(sm) : (short)0;
      }
      A1[s] = f8;
    }

    // ---- phase 1 MFMA
    f32x4 acc1[4];
#pragma unroll
    for (int t = 0; t < 4; ++t) {
      f32x4 z = {0.f, 0.f, 0.f, 0.f};
      z = __builtin_amdgcn_mfma_f32_16x16x32_bf16(A1[0], B1[t][0], z, 0, 0, 0);
      z = __builtin_amdgcn_mfma_f32_16x16x32_bf16(A1[1], B1[t][1], z, 0, 0, 0);
      acc1[t] = z;
    }

    // ---- relu+bias, pack, store [f][e] (f = t*16+lo, e = g*4..g*4+3)
#pragma unroll
    for (int t = 0; t < 4; ++t) {
      const float v0 = fmaxf(acc1[t][0] + b1v[t], 0.f);
      const float v1 = fmaxf(acc1[t][1] + b1v[t], 0.f);
      const float v2 = fmaxf(acc1[t][2] + b1v[t], 0.f);
      const float v3 = fmaxf(acc1[t][3] + b1v[t], 0.f);
      int2v pk;
      pk[0] = (int)((unsigned)f2bf(v0) | ((unsigned)f2bf(v1) << 16));
      pk[1] = (int)((unsigned)f2bf(v2) | ((unsigned)f2bf(v3) << 16));
      *(int2v*)&h1buf[wave][t * 16 + lo][g * 4] = pk;
    }
    // (compiler inserts the lgkmcnt wait: same-array LDS dependency)

    // ---- A2: column slice (e = lo, f_in = s*32+g*8+i)
    short8v A2[2];
#pragma unroll
    for (int s = 0; s < 2; ++s) {
      short8v f8;
#pragma unroll
      for (int i = 0; i < 8; ++i)
        f8[i] = (short)h1buf[wave][s * 32 + g * 8 + i][lo];
      A2[s] = f8;
    }

    // ---- phase 2 MFMA
    f32x4 acc2[4];
#pragma unroll
    for (int t = 0; t < 4; ++t) {
      f32x4 z = {0.f, 0.f, 0.f, 0.f};
      z = __builtin_amdgcn_mfma_f32_16x16x32_bf16(A2[0], B2[t][0], z, 0, 0, 0);
      z = __builtin_amdgcn_mfma_f32_16x16x32_bf16(A2[1], B2[t][1], z, 0, 0, 0);
      acc2[t] = z;
    }

    // ---- cutoff + multiply + packed-bf16 scatter (e = g*4+r)
#pragma unroll
    for (int r = 0; r < 4; ++r) {
      const int er = e0 + g * 4 + r;
      const float dw = ew[er];
      const int dst  = ei[NEDGES + er];
      const float C  = 0.5f * (__cosf(dw * (F_PI / F_CUTOFF)) + 1.0f);
      unsigned short* ap = agg + (size_t)dst * NF + 2 * lo;

      const float w0 = (acc2[0][r] + b2v[0]) * C;   // filter 2lo
      const float w1v = (acc2[1][r] + b2v[1]) * C;  // filter 2lo+1
      const float w2v = (acc2[2][r] + b2v[2]) * C;  // filter 32+2lo
      const float w3v = (acc2[3][r] + b2v[3]) * C;  // filter 33+2lo

      const float m0 = bf2f(hp0[r] & 0xffffu) * w0;
      const float m1 = bf2f(hp0[r] >> 16)     * w1v;
      const float m2 = bf2f(hp1[r] & 0xffffu) * w2v;
      const float m3 = bf2f(hp1[r] >> 16)     * w3v;

      const unsigned int pk0 = (unsigned)f2bf(m0) | ((unsigned)f2bf(m1) << 16);
      const unsigned int pk1 = (unsigned)f2bf(m2) | ((unsigned)f2bf(m3) << 16);
      asm volatile("global_atomic_pk_add_bf16 %0, %1, off"
                   :: "v"(ap), "v"(pk0));
      asm volatile("global_atomic_pk_add_bf16 %0, %1, off"
                   :: "v"(ap + 32), "v"(pk1));
    }
  }
}

// ---------------- kernel 3: out[n][d] = x[n][d] + relu(b[d] + agg[n,:] . lin2_w[d,:]) ----------------
__global__ __launch_bounds__(256) void k_out(
    const float* __restrict__ x, const unsigned short* __restrict__ agg,
    const float* __restrict__ w2, const float* __restrict__ b,
    float* __restrict__ out) {
  __shared__ __align__(16) float sw[DIM][NF + 4];
  __shared__ __align__(16) float sa[4][4][NF];
  for (int i = threadIdx.x; i < DIM * NF; i += 256)
    sw[i >> 6][i & 63] = w2[i];
  __syncthreads();
  const int wave = threadIdx.x >> 6, lane = threadIdx.x & 63;
  const float bias0 = b[lane], bias1 = b[lane + 64];
  const int nIter = NNODES / 4;
  for (int it = blockIdx.x * 4 + wave; it < nIter; it += gridDim.x * 4) {
    const int n0 = it * 4;
#pragma unroll
    for (int i = 0; i < 4; ++i)
      sa[wave][i][lane] = bf2f((unsigned)agg[(size_t)(n0 + i) * NF + lane]);
    float acc[8];
#pragma unroll
    for (int i = 0; i < 4; ++i) { acc[2 * i] = bias0; acc[2 * i + 1] = bias1; }
#pragma unroll
    for (int j4 = 0; j4 < NF / 4; ++j4) {
      const float4 wv0 = *(const float4*)&sw[lane][j4 * 4];
      const float4 wv1 = *(const float4*)&sw[lane + 64][j4 * 4];
#pragma unroll
      for (int i = 0; i < 4; ++i) {
        const float4 av = *(const float4*)&sa[wave][i][j4 * 4];
        acc[2 * i]     = fmaf(wv0.x, av.x, acc[2 * i]);
        acc[2 * i]     = fmaf(wv0.y, av.y, acc[2 * i]);
        acc[2 * i]     = fmaf(wv0.z, av.z, acc[2 * i]);
        acc[2 * i]     = fmaf(wv0.w, av.w, acc[2 * i]);
        acc[2 * i + 1] = fmaf(wv1.x, av.x, acc[2 * i + 1]);
        acc[2 * i + 1] = fmaf(wv1.y, av.y, acc[2 * i + 1]);
        acc[2 * i + 1] = fmaf(wv1.z, av.z, acc[2 * i + 1]);
        acc[2 * i + 1] = fmaf(wv1.w, av.w, acc[2 * i + 1]);
      }
    }
#pragma unroll
    for (int i = 0; i < 4; ++i) {
      const size_t base = (size_t)(n0 + i) * DIM;
      out[base + lane]      = x[base + lane]      + fmaxf(acc[2 * i],     0.f);
      out[base + 64 + lane] = x[base + 64 + lane] + fmaxf(acc[2 * i + 1], 0.f);
    }
  }
}

extern "C" void kernel_launch(void* const* d_in, const int* in_sizes, int n_in,
                              void* d_out, int out_size, void* d_ws, size_t ws_size,
                              hipStream_t stream) {
  const float* x   = (const float*)d_in[0];
  const int*   ei  = (const int*)  d_in[1];
  const float* ew  = (const float*)d_in[2];
  const float* ea  = (const float*)d_in[3];
  const float* l1w = (const float*)d_in[4];
  const float* l2w = (const float*)d_in[5];
  const float* l2b = (const float*)d_in[6];
  const float* e1w = (const float*)d_in[7];
  const float* e1b = (const float*)d_in[8];
  const float* e2w = (const float*)d_in[9];
  const float* e2b = (const float*)d_in[10];
  float* out = (float*)d_out;

  unsigned short* hbf = (unsigned short*)d_ws;                 // 100000*64 bf16 = 12.8 MB
  unsigned short* agg = hbf + (size_t)NNODES * NF;             // 100000*64 bf16 = 12.8 MB

  hipMemsetAsync(agg, 0, sizeof(unsigned short) * (size_t)NNODES * NF, stream);
  k_lin1     <<<2048, 256, 0, stream>>>(x, l1w, hbf);
  k_edge_mfma<<<2048, 256, 0, stream>>>(ei, ew, ea, hbf, e1w, e1b, e2w, e2b, agg);
  k_out      <<<2048, 256, 0, stream>>>(x, agg, l2w, l2b, out);
}